// Round 8
// baseline (354.597 us; speedup 1.0000x reference)
//
#include <hip/hip_runtime.h>
#include <hip/hip_bf16.h>
#include <hip/hip_fp16.h>

#define NN 100000
#define NE 1600000
#define D_IN 7
#define H1 64
#define H2 32
#define NG 64
#define TE 2048          // edges per bin tile
#define NTILE 782        // ceil(NE/TE)
#define BSH 9            // bucket = dst >> 9  (512 nodes/bucket)
#define NBUK 196         // ceil(NN/512)

// ---------------- bucket histogram ----------------
__global__ __launch_bounds__(256) void k_bcount(const int* __restrict__ dst,
                                                int* __restrict__ bucket_cnt) {
    __shared__ int h[NBUK];
    int t = threadIdx.x;
    for (int i = t; i < NBUK; i += 256) h[i] = 0;
    __syncthreads();
    int base = blockIdx.x * TE;
#pragma unroll
    for (int k = 0; k < TE / 256; k++) {
        int i = base + k * 256 + t;
        if (i < NE) atomicAdd(&h[dst[i] >> BSH], 1);
    }
    __syncthreads();
    for (int i = t; i < NBUK; i += 256) if (h[i]) atomicAdd(&bucket_cnt[i], h[i]);
}

// ---------------- scan bucket totals ----------------
__global__ void k_bscan(const int* __restrict__ bucket_cnt, int* __restrict__ bucket_base,
                        int* __restrict__ bucket_cursor, int* __restrict__ row_start) {
    __shared__ int s[256];
    int t = threadIdx.x;
    int v = (t < NBUK) ? bucket_cnt[t] : 0;
    s[t] = v;
    __syncthreads();
    for (int off = 1; off < 256; off <<= 1) {
        int add = (t >= off) ? s[t - off] : 0;
        __syncthreads();
        s[t] += add;
        __syncthreads();
    }
    if (t < NBUK) {
        int excl = s[t] - v;
        bucket_base[t] = excl;
        bucket_cursor[t] = excl;
    }
    if (t == 0) { bucket_base[NBUK] = NE; row_start[NN] = NE; }
}

// ---------------- bin edges into bucket-grouped staging (coalesced flush) ----------------
__global__ __launch_bounds__(256) void k_bin(const int* __restrict__ src,
                                             const int* __restrict__ dst,
                                             int* __restrict__ bucket_cursor,
                                             int2* __restrict__ staging) {
    __shared__ int hist[NBUK];
    __shared__ int startx[NBUK];
    __shared__ int runb[NBUK];
    __shared__ int cur[NBUK];
    __shared__ int sc[256];
    __shared__ int2 pairs[TE];
    int t = threadIdx.x;
    int base = blockIdx.x * TE;
    int tile_cnt = min(TE, NE - base);
    for (int i = t; i < NBUK; i += 256) hist[i] = 0;
    __syncthreads();
    int myd[TE / 256], mys[TE / 256];
#pragma unroll
    for (int k = 0; k < TE / 256; k++) {
        int i = base + k * 256 + t;
        if (i < NE) {
            myd[k] = dst[i]; mys[k] = src[i];
            atomicAdd(&hist[myd[k] >> BSH], 1);
        } else myd[k] = -1;
    }
    __syncthreads();
    int hv = (t < NBUK) ? hist[t] : 0;
    sc[t] = hv;
    __syncthreads();
    for (int off = 1; off < 256; off <<= 1) {
        int add = (t >= off) ? sc[t - off] : 0;
        __syncthreads();
        sc[t] += add;
        __syncthreads();
    }
    if (t < NBUK) {
        int ex = sc[t] - hv;
        startx[t] = ex;
        cur[t] = ex;
        if (hv > 0) runb[t] = atomicAdd(&bucket_cursor[t], hv);
    }
    __syncthreads();
#pragma unroll
    for (int k = 0; k < TE / 256; k++) {
        if (myd[k] >= 0) {
            int b = myd[k] >> BSH;
            int slot = atomicAdd(&cur[b], 1);
            pairs[slot] = make_int2(myd[k], mys[k]);
        }
    }
    __syncthreads();
    for (int i = t; i < tile_cnt; i += 256) {
        int2 p = pairs[i];
        int b = p.x >> BSH;
        staging[runb[b] + (i - startx[b])] = p;
    }
}

// ---------------- per-bucket CSR finalize: row offsets, dis, dense scatter ----------------
__global__ __launch_bounds__(512) void k_build(const int2* __restrict__ staging,
                                               const int* __restrict__ bucket_base,
                                               int* __restrict__ row_start,
                                               float* __restrict__ dis,
                                               int* __restrict__ csr) {
    __shared__ int cnt[512];
    __shared__ int offs[512];
    __shared__ int cur[512];
    int t = threadIdx.x;
    int nbase = blockIdx.x << BSH;
    int ebase = bucket_base[blockIdx.x], eend = bucket_base[blockIdx.x + 1];
    cnt[t] = 0;
    __syncthreads();
    for (int i = ebase + t; i < eend; i += 512)
        atomicAdd(&cnt[staging[i].x - nbase], 1);
    __syncthreads();
    int v = cnt[t];
    offs[t] = v;
    __syncthreads();
    for (int off = 1; off < 512; off <<= 1) {
        int add = (t >= off) ? offs[t - off] : 0;
        __syncthreads();
        offs[t] += add;
        __syncthreads();
    }
    int excl = offs[t] - v;
    cur[t] = excl;
    int node = nbase + t;
    if (node < NN) {
        row_start[node] = ebase + excl;
        dis[node] = rsqrtf((float)v + 1.0f);
    }
    __syncthreads();
    for (int i = ebase + t; i < eend; i += 512) {
        int2 p = staging[i];
        int pos = ebase + atomicAdd(&cur[p.x - nbase], 1);
        csr[pos] = p.y;
    }
}

// ---------------- mean pool over sorted batch ----------------
__device__ int lower_bound_i(const int* a, int n, int v) {
    int lo = 0, hi = n;
    while (lo < hi) { int mid = (lo + hi) >> 1; if (a[mid] < v) lo = mid + 1; else hi = mid; }
    return lo;
}

__global__ void k_pool(const float* __restrict__ x, const int* __restrict__ batch,
                       float* __restrict__ outp) {
    __shared__ int bounds[2];
    __shared__ float red[256 * D_IN];
    int g = blockIdx.x, t = threadIdx.x;
    if (t == 0) {
        bounds[0] = lower_bound_i(batch, NN, g);
        bounds[1] = lower_bound_i(batch, NN, g + 1);
    }
    __syncthreads();
    int s = bounds[0], e = bounds[1];
    float acc[D_IN];
#pragma unroll
    for (int k = 0; k < D_IN; k++) acc[k] = 0.f;
    for (int n = s + t; n < e; n += 256) {
#pragma unroll
        for (int k = 0; k < D_IN; k++) acc[k] += x[n * D_IN + k];
    }
#pragma unroll
    for (int k = 0; k < D_IN; k++) red[t * D_IN + k] = acc[k];
    __syncthreads();
    if (t < D_IN) {
        float sum = 0.f;
        for (int i = 0; i < 256; i++) sum += red[i * D_IN + t];
        float cnt = (float)(e - s);
        outp[g * D_IN + t] = sum / fmaxf(cnt, 1.f);
    }
}

// ---------------- y1h = fp16( dis * (x @ W1) ) ----------------
__global__ void k_mm1(const float* __restrict__ x, const float* __restrict__ W1,
                      const float* __restrict__ dis, __half* __restrict__ y1h) {
    __shared__ float sW[D_IN * H1];
    int t = threadIdx.x;
    for (int i = t; i < D_IN * H1; i += 256) sW[i] = W1[i];
    __syncthreads();
    int idx = blockIdx.x * 256 + t;
    if (idx < NN * H1) {
        int n = idx >> 6, h = idx & 63;
        float a = 0.f;
#pragma unroll
        for (int k = 0; k < D_IN; k++) a += x[n * D_IN + k] * sW[k * H1 + h];
        y1h[idx] = __float2half(a * dis[n]);
    }
}

// convert 4 packed halves (as float2 raw) to float4
__device__ __forceinline__ float4 h4_to_f4(float2 r) {
    __half2 h0 = *reinterpret_cast<__half2*>(&r.x);
    __half2 h1 = *reinterpret_cast<__half2*>(&r.y);
    float2 f0 = __half22float2(h0);
    float2 f1 = __half22float2(h1);
    return make_float4(f0.x, f0.y, f1.x, f1.y);
}

// ---------------- layer-1 agg + fused bias/relu: h1h = fp16( dis * relu(agg1 + b1) ) ----------------
// wave per node; g = lane>>4 (edge group), l15 = lane&15 (channel quad)
__global__ __launch_bounds__(256) void k_agg1(const int* __restrict__ row_start,
                                              const float* __restrict__ dis,
                                              const int* __restrict__ csr,
                                              const __half* __restrict__ y1h,
                                              const float* __restrict__ b1,
                                              __half* __restrict__ h1h) {
    int node = (blockIdx.x * 256 + threadIdx.x) >> 6;
    int lane = threadIdx.x & 63;
    if (node >= NN) return;
    int g = lane >> 4, l15 = lane & 15;
    int start = row_start[node];
    int c = row_start[node + 1] - start;
    const float2* yb = (const float2*)y1h;
    int idx = (c > 0) ? csr[start + min(lane, c - 1)] : node;  // whole row in regs
    float4 a0 = make_float4(0.f, 0.f, 0.f, 0.f);
    float4 a1 = make_float4(0.f, 0.f, 0.f, 0.f);
    float4 a2 = make_float4(0.f, 0.f, 0.f, 0.f);
    float4 a3 = make_float4(0.f, 0.f, 0.f, 0.f);
    int c2 = min(c, 64);
    int j = 0;
    for (; j + 16 <= c2; j += 16) {       // 16 edges/iter, 4 gathers in flight
        int s0 = __shfl(idx, j + g, 64);
        int s1 = __shfl(idx, j + 4 + g, 64);
        int s2 = __shfl(idx, j + 8 + g, 64);
        int s3 = __shfl(idx, j + 12 + g, 64);
        float4 v0 = h4_to_f4(yb[(size_t)s0 * 16 + l15]);
        float4 v1 = h4_to_f4(yb[(size_t)s1 * 16 + l15]);
        float4 v2 = h4_to_f4(yb[(size_t)s2 * 16 + l15]);
        float4 v3 = h4_to_f4(yb[(size_t)s3 * 16 + l15]);
        a0.x += v0.x; a0.y += v0.y; a0.z += v0.z; a0.w += v0.w;
        a1.x += v1.x; a1.y += v1.y; a1.z += v1.z; a1.w += v1.w;
        a2.x += v2.x; a2.y += v2.y; a2.z += v2.z; a2.w += v2.w;
        a3.x += v3.x; a3.y += v3.y; a3.z += v3.z; a3.w += v3.w;
    }
    for (; j < c2; j += 4) {              // predicated tail
        bool valid = (j + g) < c2;
        int s = __shfl(idx, min(j + g, c2 - 1), 64);
        s = valid ? s : node;
        float4 v = h4_to_f4(yb[(size_t)s * 16 + l15]);
        a0.x += valid ? v.x : 0.f; a0.y += valid ? v.y : 0.f;
        a0.z += valid ? v.z : 0.f; a0.w += valid ? v.w : 0.f;
    }
    for (; j < c; j += 4) {               // degree>64 fallback (practically never)
        bool valid = (j + g) < c;
        int pos = min(start + j + g, NE - 1);
        int s = csr[pos];
        s = valid ? s : node;
        float4 v = h4_to_f4(yb[(size_t)s * 16 + l15]);
        a0.x += valid ? v.x : 0.f; a0.y += valid ? v.y : 0.f;
        a0.z += valid ? v.z : 0.f; a0.w += valid ? v.w : 0.f;
    }
    float4 tot = make_float4(a0.x + a1.x + a2.x + a3.x, a0.y + a1.y + a2.y + a3.y,
                             a0.z + a1.z + a2.z + a3.z, a0.w + a1.w + a2.w + a3.w);
    tot.x += __shfl_xor(tot.x, 16, 64); tot.x += __shfl_xor(tot.x, 32, 64);
    tot.y += __shfl_xor(tot.y, 16, 64); tot.y += __shfl_xor(tot.y, 32, 64);
    tot.z += __shfl_xor(tot.z, 16, 64); tot.z += __shfl_xor(tot.z, 32, 64);
    tot.w += __shfl_xor(tot.w, 16, 64); tot.w += __shfl_xor(tot.w, 32, 64);
    float4 sv = h4_to_f4(yb[(size_t)node * 16 + l15]);
    float dn = dis[node];
    float4 b1f = ((const float4*)b1)[l15];
    float ox = dn * fmaxf(dn * (tot.x + sv.x) + b1f.x, 0.f);
    float oy = dn * fmaxf(dn * (tot.y + sv.y) + b1f.y, 0.f);
    float oz = dn * fmaxf(dn * (tot.z + sv.z) + b1f.z, 0.f);
    float ow = dn * fmaxf(dn * (tot.w + sv.w) + b1f.w, 0.f);
    if (g == 0) {
        __half2 ha; ha.x = __float2half(ox); ha.y = __float2half(oy);
        __half2 hb; hb.x = __float2half(oz); hb.y = __float2half(ow);
        float2 st;
        st.x = *reinterpret_cast<float*>(&ha);
        st.y = *reinterpret_cast<float*>(&hb);
        ((float2*)h1h)[(size_t)node * 16 + l15] = st;
    }
}

// ---------------- layer-2 agg + in-register W2/W3 matmul + epilogue ----------------
// t[d] = dis_d*(q[d] + sum q[s]); mu = relu(t@W2+b2); lv = relu(t@W3+b3); z = eps*exp(lv)+mu
__global__ __launch_bounds__(256) void k_agg2(const int* __restrict__ row_start,
                                              const float* __restrict__ dis,
                                              const int* __restrict__ csr,
                                              const __half* __restrict__ h1h,
                                              const float* __restrict__ W2,
                                              const float* __restrict__ W3,
                                              const float* __restrict__ b2,
                                              const float* __restrict__ b3,
                                              const float* __restrict__ eps,
                                              float* __restrict__ out_z,
                                              float* __restrict__ out_mu,
                                              float* __restrict__ out_lv) {
    __shared__ float sW[64 * 64];   // sW[k*64+h]: h<32 -> W2[k][h], else W3[k][h-32]
    __shared__ float sb[64];
    int t = threadIdx.x;
    for (int i = t; i < 64 * 64; i += 256) {
        int k = i >> 6, h = i & 63;
        sW[i] = (h < 32) ? W2[k * 32 + h] : W3[k * 32 + (h - 32)];
    }
    if (t < 64) sb[t] = (t < 32) ? b2[t] : b3[t - 32];
    __syncthreads();

    int node = (blockIdx.x * 256 + t) >> 6;
    int lane = t & 63;
    if (node >= NN) return;
    int g = lane >> 4, l15 = lane & 15;
    int start = row_start[node];
    int c = row_start[node + 1] - start;
    const float2* yb = (const float2*)h1h;
    int idx = (c > 0) ? csr[start + min(lane, c - 1)] : node;
    float4 a0 = make_float4(0.f, 0.f, 0.f, 0.f);
    float4 a1 = make_float4(0.f, 0.f, 0.f, 0.f);
    float4 a2 = make_float4(0.f, 0.f, 0.f, 0.f);
    float4 a3 = make_float4(0.f, 0.f, 0.f, 0.f);
    int c2 = min(c, 64);
    int j = 0;
    for (; j + 16 <= c2; j += 16) {
        int s0 = __shfl(idx, j + g, 64);
        int s1 = __shfl(idx, j + 4 + g, 64);
        int s2 = __shfl(idx, j + 8 + g, 64);
        int s3 = __shfl(idx, j + 12 + g, 64);
        float4 v0 = h4_to_f4(yb[(size_t)s0 * 16 + l15]);
        float4 v1 = h4_to_f4(yb[(size_t)s1 * 16 + l15]);
        float4 v2 = h4_to_f4(yb[(size_t)s2 * 16 + l15]);
        float4 v3 = h4_to_f4(yb[(size_t)s3 * 16 + l15]);
        a0.x += v0.x; a0.y += v0.y; a0.z += v0.z; a0.w += v0.w;
        a1.x += v1.x; a1.y += v1.y; a1.z += v1.z; a1.w += v1.w;
        a2.x += v2.x; a2.y += v2.y; a2.z += v2.z; a2.w += v2.w;
        a3.x += v3.x; a3.y += v3.y; a3.z += v3.z; a3.w += v3.w;
    }
    for (; j < c2; j += 4) {
        bool valid = (j + g) < c2;
        int s = __shfl(idx, min(j + g, c2 - 1), 64);
        s = valid ? s : node;
        float4 v = h4_to_f4(yb[(size_t)s * 16 + l15]);
        a0.x += valid ? v.x : 0.f; a0.y += valid ? v.y : 0.f;
        a0.z += valid ? v.z : 0.f; a0.w += valid ? v.w : 0.f;
    }
    for (; j < c; j += 4) {
        bool valid = (j + g) < c;
        int pos = min(start + j + g, NE - 1);
        int s = csr[pos];
        s = valid ? s : node;
        float4 v = h4_to_f4(yb[(size_t)s * 16 + l15]);
        a0.x += valid ? v.x : 0.f; a0.y += valid ? v.y : 0.f;
        a0.z += valid ? v.z : 0.f; a0.w += valid ? v.w : 0.f;
    }
    float4 tot = make_float4(a0.x + a1.x + a2.x + a3.x, a0.y + a1.y + a2.y + a3.y,
                             a0.z + a1.z + a2.z + a3.z, a0.w + a1.w + a2.w + a3.w);
    tot.x += __shfl_xor(tot.x, 16, 64); tot.x += __shfl_xor(tot.x, 32, 64);
    tot.y += __shfl_xor(tot.y, 16, 64); tot.y += __shfl_xor(tot.y, 32, 64);
    tot.z += __shfl_xor(tot.z, 16, 64); tot.z += __shfl_xor(tot.z, 32, 64);
    tot.w += __shfl_xor(tot.w, 16, 64); tot.w += __shfl_xor(tot.w, 32, 64);
    float4 sv = h4_to_f4(yb[(size_t)node * 16 + l15]);
    float dn = dis[node];
    float4 t4 = make_float4(dn * (tot.x + sv.x), dn * (tot.y + sv.y),
                            dn * (tot.z + sv.z), dn * (tot.w + sv.w));
    // matmul: every lane computes one output channel (lane<32: mu[lane], else lv[lane-32])
    float acc = sb[lane];
#pragma unroll
    for (int k4 = 0; k4 < 16; k4++) {
        float tx = __shfl(t4.x, k4, 16);   // width-16: each group sources its own replica
        float ty = __shfl(t4.y, k4, 16);
        float tz = __shfl(t4.z, k4, 16);
        float tw = __shfl(t4.w, k4, 16);
        acc += tx * sW[(4 * k4 + 0) * 64 + lane];
        acc += ty * sW[(4 * k4 + 1) * 64 + lane];
        acc += tz * sW[(4 * k4 + 2) * 64 + lane];
        acc += tw * sW[(4 * k4 + 3) * 64 + lane];
    }
    float val = fmaxf(acc, 0.f);
    float other = __shfl_xor(val, 32, 64);
    if (lane < 32) {
        int o = node * H2 + lane;
        out_mu[o] = val;
        out_z[o] = eps[o] * __expf(other) + val;
    } else {
        out_lv[node * H2 + (lane - 32)] = val;
    }
}

extern "C" void kernel_launch(void* const* d_in, const int* in_sizes, int n_in,
                              void* d_out, int out_size, void* d_ws, size_t ws_size,
                              hipStream_t stream) {
    const float* x   = (const float*)d_in[0];
    const int*   ei  = (const int*)d_in[1];   // [2, E]
    const int*   bat = (const int*)d_in[2];
    const float* W1  = (const float*)d_in[3];
    const float* b1  = (const float*)d_in[4];
    const float* W2  = (const float*)d_in[5];
    const float* b2  = (const float*)d_in[6];
    const float* W3  = (const float*)d_in[7];
    const float* b3  = (const float*)d_in[8];
    const float* eps = (const float*)d_in[9];

    const int* src = ei;
    const int* dst = ei + NE;

    float* out = (float*)d_out;
    float* out_z    = out;                               // [N,32]
    float* out_pool = out + (size_t)NN * H2;             // [G,7]
    float* out_mu   = out_pool + NG * D_IN;              // [N,32]
    float* out_lv   = out_mu + (size_t)NN * H2;          // [N,32]

    // workspace layout (4-byte words); staging 8B-aligned (prefix word count even)
    int*    bucket_cnt    = (int*)d_ws;                      // 256
    int*    bucket_base   = bucket_cnt + 256;                // 256 (NBUK+1 used)
    int*    bucket_cursor = bucket_base + 256;               // 256
    int*    row_start     = bucket_cursor + 256;             // NN+2
    float*  dis           = (float*)(row_start + NN + 2);    // NN
    int2*   staging       = (int2*)(dis + NN);               // NE int2
    int*    csr           = (int*)(staging + NE);            // NE
    __half* y1h           = (__half*)(csr + NE);             // NN*64 halves
    __half* h1h           = y1h + (size_t)NN * H1;           // NN*64 halves

    hipMemsetAsync(bucket_cnt, 0, 256 * sizeof(int), stream);

    k_bcount<<<NTILE, 256, 0, stream>>>(dst, bucket_cnt);
    k_bscan <<<1, 256, 0, stream>>>(bucket_cnt, bucket_base, bucket_cursor, row_start);
    k_bin   <<<NTILE, 256, 0, stream>>>(src, dst, bucket_cursor, staging);
    k_build <<<NBUK, 512, 0, stream>>>(staging, bucket_base, row_start, dis, csr);

    k_pool  <<<NG, 256, 0, stream>>>(x, bat, out_pool);

    k_mm1   <<<(NN * H1 + 255) / 256, 256, 0, stream>>>(x, W1, dis, y1h);
    k_agg1  <<<(NN + 3) / 4, 256, 0, stream>>>(row_start, dis, csr, y1h, b1, h1h);
    k_agg2  <<<(NN + 3) / 4, 256, 0, stream>>>(row_start, dis, csr, h1h, W2, W3,
                                               b2, b3, eps, out_z, out_mu, out_lv);
}

// Round 9
// 299.330 us; speedup vs baseline: 1.1846x; 1.1846x over previous
//
#include <hip/hip_runtime.h>
#include <hip/hip_bf16.h>
#include <hip/hip_fp16.h>

#define NN 100000
#define NE 1600000
#define D_IN 7
#define H1 64
#define H2 32
#define NG 64
#define TE 2048          // edges per bin tile
#define NTILE 782        // ceil(NE/TE)
#define BSH 9            // bucket = dst >> 9  (512 nodes/bucket)
#define NBUK 196         // ceil(NN/512)
#define CAP 10240        // slots per bucket (mean 8192, +22 sigma)

// ---------------- init bucket cursors to b*CAP ----------------
__global__ void k_init(int* __restrict__ bucket_cursor) {
    int t = threadIdx.x;
    if (t < 256) bucket_cursor[t] = t * CAP;
}

// ---------------- bin edges into fixed-capacity buckets (coalesced flush) ----------------
__global__ __launch_bounds__(256) void k_bin(const int* __restrict__ src,
                                             const int* __restrict__ dst,
                                             int* __restrict__ bucket_cursor,
                                             int2* __restrict__ staging) {
    __shared__ int hist[NBUK];
    __shared__ int startx[NBUK];
    __shared__ int runb[NBUK];
    __shared__ int cur[NBUK];
    __shared__ int sc[256];
    __shared__ int2 pairs[TE];
    int t = threadIdx.x;
    int base = blockIdx.x * TE;
    int tile_cnt = min(TE, NE - base);
    for (int i = t; i < NBUK; i += 256) hist[i] = 0;
    __syncthreads();
    int myd[TE / 256], mys[TE / 256];
#pragma unroll
    for (int k = 0; k < TE / 256; k++) {
        int i = base + k * 256 + t;
        if (i < NE) {
            myd[k] = dst[i]; mys[k] = src[i];
            atomicAdd(&hist[myd[k] >> BSH], 1);
        } else myd[k] = -1;
    }
    __syncthreads();
    int hv = (t < NBUK) ? hist[t] : 0;
    sc[t] = hv;
    __syncthreads();
    for (int off = 1; off < 256; off <<= 1) {
        int add = (t >= off) ? sc[t - off] : 0;
        __syncthreads();
        sc[t] += add;
        __syncthreads();
    }
    if (t < NBUK) {
        int ex = sc[t] - hv;
        startx[t] = ex;
        cur[t] = ex;
        if (hv > 0) runb[t] = atomicAdd(&bucket_cursor[t], hv);
    }
    __syncthreads();
#pragma unroll
    for (int k = 0; k < TE / 256; k++) {
        if (myd[k] >= 0) {
            int b = myd[k] >> BSH;
            int slot = atomicAdd(&cur[b], 1);
            pairs[slot] = make_int2(myd[k], mys[k]);
        }
    }
    __syncthreads();
    for (int i = t; i < tile_cnt; i += 256) {
        int2 p = pairs[i];
        int b = p.x >> BSH;
        staging[runb[b] + (i - startx[b])] = p;
    }
}

// ---------------- per-bucket CSR finalize: rowinfo, dis, dense scatter ----------------
__global__ __launch_bounds__(512) void k_build(const int2* __restrict__ staging,
                                               const int* __restrict__ bucket_cursor,
                                               int2* __restrict__ rowinfo,
                                               float* __restrict__ dis,
                                               int* __restrict__ csr) {
    __shared__ int cnt[512];
    __shared__ int offs[512];
    __shared__ int cur[512];
    int t = threadIdx.x;
    int nbase = blockIdx.x << BSH;
    int ebase = blockIdx.x * CAP;
    int eend = bucket_cursor[blockIdx.x];   // ebase + count
    cnt[t] = 0;
    __syncthreads();
    for (int i = ebase + t; i < eend; i += 512)
        atomicAdd(&cnt[staging[i].x - nbase], 1);
    __syncthreads();
    int v = cnt[t];
    offs[t] = v;
    __syncthreads();
    for (int off = 1; off < 512; off <<= 1) {
        int add = (t >= off) ? offs[t - off] : 0;
        __syncthreads();
        offs[t] += add;
        __syncthreads();
    }
    int excl = offs[t] - v;
    cur[t] = excl;
    int node = nbase + t;
    if (node < NN) {
        rowinfo[node] = make_int2(ebase + excl, v);
        dis[node] = rsqrtf((float)v + 1.0f);
    }
    __syncthreads();
    for (int i = ebase + t; i < eend; i += 512) {
        int2 p = staging[i];
        int pos = ebase + atomicAdd(&cur[p.x - nbase], 1);
        csr[pos] = p.y;     // stores confined to bucket's ~40KB csr window
    }
}

// ---------------- mean pool over sorted batch ----------------
__device__ int lower_bound_i(const int* a, int n, int v) {
    int lo = 0, hi = n;
    while (lo < hi) { int mid = (lo + hi) >> 1; if (a[mid] < v) lo = mid + 1; else hi = mid; }
    return lo;
}

__global__ void k_pool(const float* __restrict__ x, const int* __restrict__ batch,
                       float* __restrict__ outp) {
    __shared__ int bounds[2];
    __shared__ float red[256 * D_IN];
    int g = blockIdx.x, t = threadIdx.x;
    if (t == 0) {
        bounds[0] = lower_bound_i(batch, NN, g);
        bounds[1] = lower_bound_i(batch, NN, g + 1);
    }
    __syncthreads();
    int s = bounds[0], e = bounds[1];
    float acc[D_IN];
#pragma unroll
    for (int k = 0; k < D_IN; k++) acc[k] = 0.f;
    for (int n = s + t; n < e; n += 256) {
#pragma unroll
        for (int k = 0; k < D_IN; k++) acc[k] += x[n * D_IN + k];
    }
#pragma unroll
    for (int k = 0; k < D_IN; k++) red[t * D_IN + k] = acc[k];
    __syncthreads();
    if (t < D_IN) {
        float sum = 0.f;
        for (int i = 0; i < 256; i++) sum += red[i * D_IN + t];
        float cnt = (float)(e - s);
        outp[g * D_IN + t] = sum / fmaxf(cnt, 1.f);
    }
}

// ---------------- y1h = fp16( dis * (x @ W1) ) ----------------
__global__ void k_mm1(const float* __restrict__ x, const float* __restrict__ W1,
                      const float* __restrict__ dis, __half* __restrict__ y1h) {
    __shared__ float sW[D_IN * H1];
    int t = threadIdx.x;
    for (int i = t; i < D_IN * H1; i += 256) sW[i] = W1[i];
    __syncthreads();
    int idx = blockIdx.x * 256 + t;
    if (idx < NN * H1) {
        int n = idx >> 6, h = idx & 63;
        float a = 0.f;
#pragma unroll
        for (int k = 0; k < D_IN; k++) a += x[n * D_IN + k] * sW[k * H1 + h];
        y1h[idx] = __float2half(a * dis[n]);
    }
}

// convert 4 packed halves (as float2 raw) to float4
__device__ __forceinline__ float4 h4_to_f4(float2 r) {
    __half2 h0 = *reinterpret_cast<__half2*>(&r.x);
    __half2 h1 = *reinterpret_cast<__half2*>(&r.y);
    float2 f0 = __half22float2(h0);
    float2 f1 = __half22float2(h1);
    return make_float4(f0.x, f0.y, f1.x, f1.y);
}

#define ACC4(A, V) { A.x += V.x; A.y += V.y; A.z += V.z; A.w += V.w; }

// ---------------- layer-1 agg + fused bias/relu: h1h = fp16( dis * relu(agg + b1) ) ----------------
// wave per node; g = lane>>4 (edge group), l15 = lane&15 (channel quad)
__global__ __launch_bounds__(256) void k_agg1(const int2* __restrict__ rowinfo,
                                              const float* __restrict__ dis,
                                              const int* __restrict__ csr,
                                              const __half* __restrict__ y1h,
                                              const float* __restrict__ b1,
                                              __half* __restrict__ h1h) {
    int node = (blockIdx.x * 256 + threadIdx.x) >> 6;
    int lane = threadIdx.x & 63;
    if (node >= NN) return;
    int g = lane >> 4, l15 = lane & 15;
    int2 ri = rowinfo[node];
    int start = ri.x, c = ri.y;
    const float2* yb = (const float2*)y1h;
    float4 a0 = make_float4(0.f, 0.f, 0.f, 0.f);
    float4 a1 = make_float4(0.f, 0.f, 0.f, 0.f);
    float4 a2 = make_float4(0.f, 0.f, 0.f, 0.f);
    float4 a3 = make_float4(0.f, 0.f, 0.f, 0.f);
    int j = 0;
    for (; j + 16 <= c; j += 16) {          // 16 edges/iter, 4 gathers in flight
        int s0 = csr[start + j + g];
        int s1 = csr[start + j + 4 + g];
        int s2 = csr[start + j + 8 + g];
        int s3 = csr[start + j + 12 + g];
        float4 v0 = h4_to_f4(yb[(size_t)s0 * 16 + l15]);
        float4 v1 = h4_to_f4(yb[(size_t)s1 * 16 + l15]);
        float4 v2 = h4_to_f4(yb[(size_t)s2 * 16 + l15]);
        float4 v3 = h4_to_f4(yb[(size_t)s3 * 16 + l15]);
        ACC4(a0, v0); ACC4(a1, v1); ACC4(a2, v2); ACC4(a3, v3);
    }
    for (; j + 8 <= c; j += 8) {            // 8 edges, 2 gathers in flight
        int s0 = csr[start + j + g];
        int s1 = csr[start + j + 4 + g];
        float4 v0 = h4_to_f4(yb[(size_t)s0 * 16 + l15]);
        float4 v1 = h4_to_f4(yb[(size_t)s1 * 16 + l15]);
        ACC4(a0, v0); ACC4(a1, v1);
    }
    for (; j < c; j += 4) {                 // predicated tail; clamp inside OWN row
        bool valid = (j + g) < c;
        int s = csr[start + min(j + g, c - 1)];
        s = valid ? s : node;
        float4 v = h4_to_f4(yb[(size_t)s * 16 + l15]);
        a0.x += valid ? v.x : 0.f; a0.y += valid ? v.y : 0.f;
        a0.z += valid ? v.z : 0.f; a0.w += valid ? v.w : 0.f;
    }
    float4 tot = make_float4(a0.x + a1.x + a2.x + a3.x, a0.y + a1.y + a2.y + a3.y,
                             a0.z + a1.z + a2.z + a3.z, a0.w + a1.w + a2.w + a3.w);
    tot.x += __shfl_xor(tot.x, 16, 64); tot.x += __shfl_xor(tot.x, 32, 64);
    tot.y += __shfl_xor(tot.y, 16, 64); tot.y += __shfl_xor(tot.y, 32, 64);
    tot.z += __shfl_xor(tot.z, 16, 64); tot.z += __shfl_xor(tot.z, 32, 64);
    tot.w += __shfl_xor(tot.w, 16, 64); tot.w += __shfl_xor(tot.w, 32, 64);
    float4 sv = h4_to_f4(yb[(size_t)node * 16 + l15]);
    float dn = dis[node];
    float4 b1f = ((const float4*)b1)[l15];
    float ox = dn * fmaxf(dn * (tot.x + sv.x) + b1f.x, 0.f);
    float oy = dn * fmaxf(dn * (tot.y + sv.y) + b1f.y, 0.f);
    float oz = dn * fmaxf(dn * (tot.z + sv.z) + b1f.z, 0.f);
    float ow = dn * fmaxf(dn * (tot.w + sv.w) + b1f.w, 0.f);
    if (g == 0) {
        __half2 ha; ha.x = __float2half(ox); ha.y = __float2half(oy);
        __half2 hb; hb.x = __float2half(oz); hb.y = __float2half(ow);
        float2 st;
        st.x = *reinterpret_cast<float*>(&ha);
        st.y = *reinterpret_cast<float*>(&hb);
        ((float2*)h1h)[(size_t)node * 16 + l15] = st;
    }
}

// ---------------- y23h = fp16( h1h @ (W2 ‖ W3) ), interleaved mu/lv rows ----------------
// h1h already contains dis*relu(agg1+b1) -> dis factor passes through the matmul
__global__ void k_mm2(const __half* __restrict__ h1h,
                      const float* __restrict__ W2, const float* __restrict__ W3,
                      __half* __restrict__ y23h) {
    __shared__ float sW2[H1 * H2];
    __shared__ float sW3[H1 * H2];
    __shared__ float sh[8 * H1];
    int t = threadIdx.x;
    for (int i = t; i < H1 * H2; i += 256) { sW2[i] = W2[i]; sW3[i] = W3[i]; }
    int base_n = blockIdx.x * 8;
    const __half2* hp = (const __half2*)h1h;
    for (int i = t; i < 8 * 32; i += 256) {      // 256 half2 loads
        int n = base_n + (i >> 5);
        float2 f = (n < NN) ? __half22float2(hp[(size_t)n * 32 + (i & 31)])
                            : make_float2(0.f, 0.f);
        ((float2*)sh)[i] = f;
    }
    __syncthreads();
    int n = base_n + (t >> 5), h = t & 31;
    if (n < NN) {
        float a2 = 0.f, a3 = 0.f;
        const float* hr = &sh[(t >> 5) * H1];
#pragma unroll
        for (int k = 0; k < H1; k++) {
            float hv = hr[k];
            a2 += hv * sW2[k * H2 + h];
            a3 += hv * sW3[k * H2 + h];
        }
        y23h[(size_t)n * 64 + h]      = __float2half(a2);
        y23h[(size_t)n * 64 + 32 + h] = __float2half(a3);
    }
}

// ---------------- layer-2 aggregation + fused epilogue, 4 gathers in flight ----------------
// y23h row: halves 0..31 = mu-path, 32..63 = logvar-path. channel = 4*l15+k (mod 32)
__global__ __launch_bounds__(256) void k_agg2(const int2* __restrict__ rowinfo,
                                              const float* __restrict__ dis,
                                              const int* __restrict__ csr,
                                              const __half* __restrict__ y23h,
                                              const float* __restrict__ b2,
                                              const float* __restrict__ b3,
                                              const float* __restrict__ eps,
                                              float* __restrict__ out_z,
                                              float* __restrict__ out_mu,
                                              float* __restrict__ out_lv) {
    int node = (blockIdx.x * 256 + threadIdx.x) >> 6;
    int lane = threadIdx.x & 63;
    if (node >= NN) return;
    int g = lane >> 4, l15 = lane & 15;
    int2 ri = rowinfo[node];
    int start = ri.x, c = ri.y;
    const float2* yb = (const float2*)y23h;
    float4 a0 = make_float4(0.f, 0.f, 0.f, 0.f);
    float4 a1 = make_float4(0.f, 0.f, 0.f, 0.f);
    float4 a2 = make_float4(0.f, 0.f, 0.f, 0.f);
    float4 a3 = make_float4(0.f, 0.f, 0.f, 0.f);
    int j = 0;
    for (; j + 16 <= c; j += 16) {
        int s0 = csr[start + j + g];
        int s1 = csr[start + j + 4 + g];
        int s2 = csr[start + j + 8 + g];
        int s3 = csr[start + j + 12 + g];
        float4 v0 = h4_to_f4(yb[(size_t)s0 * 16 + l15]);
        float4 v1 = h4_to_f4(yb[(size_t)s1 * 16 + l15]);
        float4 v2 = h4_to_f4(yb[(size_t)s2 * 16 + l15]);
        float4 v3 = h4_to_f4(yb[(size_t)s3 * 16 + l15]);
        ACC4(a0, v0); ACC4(a1, v1); ACC4(a2, v2); ACC4(a3, v3);
    }
    for (; j + 8 <= c; j += 8) {
        int s0 = csr[start + j + g];
        int s1 = csr[start + j + 4 + g];
        float4 v0 = h4_to_f4(yb[(size_t)s0 * 16 + l15]);
        float4 v1 = h4_to_f4(yb[(size_t)s1 * 16 + l15]);
        ACC4(a0, v0); ACC4(a1, v1);
    }
    for (; j < c; j += 4) {
        bool valid = (j + g) < c;
        int s = csr[start + min(j + g, c - 1)];
        s = valid ? s : node;
        float4 v = h4_to_f4(yb[(size_t)s * 16 + l15]);
        a0.x += valid ? v.x : 0.f; a0.y += valid ? v.y : 0.f;
        a0.z += valid ? v.z : 0.f; a0.w += valid ? v.w : 0.f;
    }
    float4 tot = make_float4(a0.x + a1.x + a2.x + a3.x, a0.y + a1.y + a2.y + a3.y,
                             a0.z + a1.z + a2.z + a3.z, a0.w + a1.w + a2.w + a3.w);
    tot.x += __shfl_xor(tot.x, 16, 64); tot.x += __shfl_xor(tot.x, 32, 64);
    tot.y += __shfl_xor(tot.y, 16, 64); tot.y += __shfl_xor(tot.y, 32, 64);
    tot.z += __shfl_xor(tot.z, 16, 64); tot.z += __shfl_xor(tot.z, 32, 64);
    tot.w += __shfl_xor(tot.w, 16, 64); tot.w += __shfl_xor(tot.w, 32, 64);
    float4 sv = h4_to_f4(yb[(size_t)node * 16 + l15]);
    float dn = dis[node];
    float4 bias = (l15 < 8) ? ((const float4*)b2)[l15] : ((const float4*)b3)[l15 - 8];
    float4 val;
    val.x = fmaxf(dn * (tot.x + sv.x) + bias.x, 0.f);
    val.y = fmaxf(dn * (tot.y + sv.y) + bias.y, 0.f);
    val.z = fmaxf(dn * (tot.z + sv.z) + bias.z, 0.f);
    val.w = fmaxf(dn * (tot.w + sv.w) + bias.w, 0.f);
    float4 other;
    other.x = __shfl_xor(val.x, 8, 64);
    other.y = __shfl_xor(val.y, 8, 64);
    other.z = __shfl_xor(val.z, 8, 64);
    other.w = __shfl_xor(val.w, 8, 64);
    if (g == 0) {
        if (l15 < 8) {
            size_t q = (size_t)node * 8 + l15;
            ((float4*)out_mu)[q] = val;
            float4 ev = ((const float4*)eps)[q];
            float4 z;
            z.x = ev.x * __expf(other.x) + val.x;
            z.y = ev.y * __expf(other.y) + val.y;
            z.z = ev.z * __expf(other.z) + val.z;
            z.w = ev.w * __expf(other.w) + val.w;
            ((float4*)out_z)[q] = z;
        } else {
            ((float4*)out_lv)[(size_t)node * 8 + (l15 - 8)] = val;
        }
    }
}

extern "C" void kernel_launch(void* const* d_in, const int* in_sizes, int n_in,
                              void* d_out, int out_size, void* d_ws, size_t ws_size,
                              hipStream_t stream) {
    const float* x   = (const float*)d_in[0];
    const int*   ei  = (const int*)d_in[1];   // [2, E]
    const int*   bat = (const int*)d_in[2];
    const float* W1  = (const float*)d_in[3];
    const float* b1  = (const float*)d_in[4];
    const float* W2  = (const float*)d_in[5];
    const float* b2  = (const float*)d_in[6];
    const float* W3  = (const float*)d_in[7];
    const float* b3  = (const float*)d_in[8];
    const float* eps = (const float*)d_in[9];

    const int* src = ei;
    const int* dst = ei + NE;

    float* out = (float*)d_out;
    float* out_z    = out;                               // [N,32]
    float* out_pool = out + (size_t)NN * H2;             // [G,7]
    float* out_mu   = out_pool + NG * D_IN;              // [N,32]
    float* out_lv   = out_mu + (size_t)NN * H2;          // [N,32]

    // workspace layout (8B-aligned segments)
    int*    bucket_cursor = (int*)d_ws;                          // 256
    int2*   rowinfo       = (int2*)(bucket_cursor + 256);        // NN (start,cnt)
    float*  dis           = (float*)(rowinfo + NN);              // NN
    int2*   staging       = (int2*)(dis + NN);                   // NBUK*CAP
    int*    csr           = (int*)(staging + (size_t)NBUK * CAP);// NBUK*CAP
    __half* y1h           = (__half*)(csr + (size_t)NBUK * CAP); // NN*64 halves
    __half* h1h           = y1h + (size_t)NN * H1;               // NN*64 halves
    __half* y23h          = y1h;                                 // alias: y1h dead after k_agg1

    k_init  <<<1, 256, 0, stream>>>(bucket_cursor);
    k_bin   <<<NTILE, 256, 0, stream>>>(src, dst, bucket_cursor, staging);
    k_build <<<NBUK, 512, 0, stream>>>(staging, bucket_cursor, rowinfo, dis, csr);

    k_pool  <<<NG, 256, 0, stream>>>(x, bat, out_pool);

    k_mm1   <<<(NN * H1 + 255) / 256, 256, 0, stream>>>(x, W1, dis, y1h);
    k_agg1  <<<(NN + 3) / 4, 256, 0, stream>>>(rowinfo, dis, csr, y1h, b1, h1h);
    k_mm2   <<<(NN + 7) / 8, 256, 0, stream>>>(h1h, W2, W3, y23h);
    k_agg2  <<<(NN + 3) / 4, 256, 0, stream>>>(rowinfo, dis, csr, y23h,
                                               b2, b3, eps, out_z, out_mu, out_lv);
}

// Round 10
// 296.082 us; speedup vs baseline: 1.1976x; 1.0110x over previous
//
#include <hip/hip_runtime.h>
#include <hip/hip_bf16.h>
#include <hip/hip_fp16.h>

#define NN 100000
#define NE 1600000
#define D_IN 7
#define H1 64
#define H2 32
#define NG 64
#define TE 2048          // edges per bin tile
#define NTILE 782        // ceil(NE/TE)
#define BSH 9            // bucket = dst >> 9  (512 nodes/bucket)
#define NBUK 196         // ceil(NN/512)
#define CAP 10240        // slots per bucket (mean 8192, +22 sigma)

// ---------------- init bucket cursors to b*CAP ----------------
__global__ void k_init(int* __restrict__ bucket_cursor) {
    int t = threadIdx.x;
    if (t < 256) bucket_cursor[t] = t * CAP;
}

// ---------------- bin edges into fixed-capacity buckets (coalesced flush) ----------------
__global__ __launch_bounds__(256) void k_bin(const int* __restrict__ src,
                                             const int* __restrict__ dst,
                                             int* __restrict__ bucket_cursor,
                                             int2* __restrict__ staging) {
    __shared__ int hist[NBUK];
    __shared__ int startx[NBUK];
    __shared__ int runb[NBUK];
    __shared__ int cur[NBUK];
    __shared__ int sc[256];
    __shared__ int2 pairs[TE];
    int t = threadIdx.x;
    int base = blockIdx.x * TE;
    int tile_cnt = min(TE, NE - base);
    for (int i = t; i < NBUK; i += 256) hist[i] = 0;
    __syncthreads();
    int myd[TE / 256], mys[TE / 256];
#pragma unroll
    for (int k = 0; k < TE / 256; k++) {
        int i = base + k * 256 + t;
        if (i < NE) {
            myd[k] = dst[i]; mys[k] = src[i];
            atomicAdd(&hist[myd[k] >> BSH], 1);
        } else myd[k] = -1;
    }
    __syncthreads();
    int hv = (t < NBUK) ? hist[t] : 0;
    sc[t] = hv;
    __syncthreads();
    for (int off = 1; off < 256; off <<= 1) {
        int add = (t >= off) ? sc[t - off] : 0;
        __syncthreads();
        sc[t] += add;
        __syncthreads();
    }
    if (t < NBUK) {
        int ex = sc[t] - hv;
        startx[t] = ex;
        cur[t] = ex;
        if (hv > 0) runb[t] = atomicAdd(&bucket_cursor[t], hv);
    }
    __syncthreads();
#pragma unroll
    for (int k = 0; k < TE / 256; k++) {
        if (myd[k] >= 0) {
            int b = myd[k] >> BSH;
            int slot = atomicAdd(&cur[b], 1);
            pairs[slot] = make_int2(myd[k], mys[k]);
        }
    }
    __syncthreads();
    for (int i = t; i < tile_cnt; i += 256) {
        int2 p = pairs[i];
        int b = p.x >> BSH;
        staging[runb[b] + (i - startx[b])] = p;
    }
}

// ---------------- per-bucket CSR finalize: rowinfo, dis, dense scatter ----------------
__global__ __launch_bounds__(512) void k_build(const int2* __restrict__ staging,
                                               const int* __restrict__ bucket_cursor,
                                               int2* __restrict__ rowinfo,
                                               float* __restrict__ dis,
                                               int* __restrict__ csr) {
    __shared__ int cnt[512];
    __shared__ int offs[512];
    __shared__ int cur[512];
    int t = threadIdx.x;
    int nbase = blockIdx.x << BSH;
    int ebase = blockIdx.x * CAP;
    int eend = bucket_cursor[blockIdx.x];   // ebase + count
    cnt[t] = 0;
    __syncthreads();
    for (int i = ebase + t; i < eend; i += 512)
        atomicAdd(&cnt[staging[i].x - nbase], 1);
    __syncthreads();
    int v = cnt[t];
    offs[t] = v;
    __syncthreads();
    for (int off = 1; off < 512; off <<= 1) {
        int add = (t >= off) ? offs[t - off] : 0;
        __syncthreads();
        offs[t] += add;
        __syncthreads();
    }
    int excl = offs[t] - v;
    cur[t] = excl;
    int node = nbase + t;
    if (node < NN) {
        rowinfo[node] = make_int2(ebase + excl, v);
        dis[node] = rsqrtf((float)v + 1.0f);
    }
    __syncthreads();
    for (int i = ebase + t; i < eend; i += 512) {
        int2 p = staging[i];
        int pos = ebase + atomicAdd(&cur[p.x - nbase], 1);
        csr[pos] = p.y;     // stores confined to bucket's ~40KB csr window
    }
}

// ---------------- mean pool over sorted batch ----------------
__device__ int lower_bound_i(const int* a, int n, int v) {
    int lo = 0, hi = n;
    while (lo < hi) { int mid = (lo + hi) >> 1; if (a[mid] < v) lo = mid + 1; else hi = mid; }
    return lo;
}

__global__ void k_pool(const float* __restrict__ x, const int* __restrict__ batch,
                       float* __restrict__ outp) {
    __shared__ int bounds[2];
    __shared__ float red[256 * D_IN];
    int g = blockIdx.x, t = threadIdx.x;
    if (t == 0) {
        bounds[0] = lower_bound_i(batch, NN, g);
        bounds[1] = lower_bound_i(batch, NN, g + 1);
    }
    __syncthreads();
    int s = bounds[0], e = bounds[1];
    float acc[D_IN];
#pragma unroll
    for (int k = 0; k < D_IN; k++) acc[k] = 0.f;
    for (int n = s + t; n < e; n += 256) {
#pragma unroll
        for (int k = 0; k < D_IN; k++) acc[k] += x[n * D_IN + k];
    }
#pragma unroll
    for (int k = 0; k < D_IN; k++) red[t * D_IN + k] = acc[k];
    __syncthreads();
    if (t < D_IN) {
        float sum = 0.f;
        for (int i = 0; i < 256; i++) sum += red[i * D_IN + t];
        float cnt = (float)(e - s);
        outp[g * D_IN + t] = sum / fmaxf(cnt, 1.f);
    }
}

// ---------------- y1h = fp16( dis * (x @ W1) ) ----------------
__global__ void k_mm1(const float* __restrict__ x, const float* __restrict__ W1,
                      const float* __restrict__ dis, __half* __restrict__ y1h) {
    __shared__ float sW[D_IN * H1];
    int t = threadIdx.x;
    for (int i = t; i < D_IN * H1; i += 256) sW[i] = W1[i];
    __syncthreads();
    int idx = blockIdx.x * 256 + t;
    if (idx < NN * H1) {
        int n = idx >> 6, h = idx & 63;
        float a = 0.f;
#pragma unroll
        for (int k = 0; k < D_IN; k++) a += x[n * D_IN + k] * sW[k * H1 + h];
        y1h[idx] = __float2half(a * dis[n]);
    }
}

// convert 4 packed halves (as float2 raw) to float4
__device__ __forceinline__ float4 h4_to_f4(float2 r) {
    __half2 h0 = *reinterpret_cast<__half2*>(&r.x);
    __half2 h1 = *reinterpret_cast<__half2*>(&r.y);
    float2 f0 = __half22float2(h0);
    float2 f1 = __half22float2(h1);
    return make_float4(f0.x, f0.y, f1.x, f1.y);
}

// packed accumulate: A += (half2 pair viewed from float2)
#define PKACC(P, Q, R) { \
    const __half2* _h = reinterpret_cast<const __half2*>(&R); \
    P = __hadd2(P, _h[0]); Q = __hadd2(Q, _h[1]); }

// butterfly-reduce packed half2 pair across the 4 lane-groups (xor 16, 32)
#define PKBFLY(P, Q) { \
    unsigned int _ip, _iq, _op, _oq; \
    _ip = *reinterpret_cast<unsigned int*>(&P); \
    _iq = *reinterpret_cast<unsigned int*>(&Q); \
    _op = (unsigned int)__shfl_xor((int)_ip, 16, 64); \
    _oq = (unsigned int)__shfl_xor((int)_iq, 16, 64); \
    P = __hadd2(P, *reinterpret_cast<__half2*>(&_op)); \
    Q = __hadd2(Q, *reinterpret_cast<__half2*>(&_oq)); \
    _ip = *reinterpret_cast<unsigned int*>(&P); \
    _iq = *reinterpret_cast<unsigned int*>(&Q); \
    _op = (unsigned int)__shfl_xor((int)_ip, 32, 64); \
    _oq = (unsigned int)__shfl_xor((int)_iq, 32, 64); \
    P = __hadd2(P, *reinterpret_cast<__half2*>(&_op)); \
    Q = __hadd2(Q, *reinterpret_cast<__half2*>(&_oq)); }

// ---------------- layer-1 agg + fused bias/relu: h1h = fp16( dis * relu(agg + b1) ) ----------------
// wave per node; g = lane>>4 (edge group), l15 = lane&15 (channel quad)
__global__ __launch_bounds__(256) void k_agg1(const int2* __restrict__ rowinfo,
                                              const float* __restrict__ dis,
                                              const int* __restrict__ csr,
                                              const __half* __restrict__ y1h,
                                              const float* __restrict__ b1,
                                              __half* __restrict__ h1h) {
    int node = (blockIdx.x * 256 + threadIdx.x) >> 6;
    int lane = threadIdx.x & 63;
    if (node >= NN) return;
    int g = lane >> 4, l15 = lane & 15;
    int2 ri = rowinfo[node];
    int start = ri.x, c = ri.y;
    const float2* yb = (const float2*)y1h;
    __half2 z = __float2half2_rn(0.f);
    __half2 p0 = z, p1 = z, p2 = z, p3 = z;
    __half2 q0 = z, q1 = z, q2 = z, q3 = z;
    int j = 0;
    for (; j + 16 <= c; j += 16) {          // 16 edges/iter, 4 gathers in flight
        int s0 = csr[start + j + g];
        int s1 = csr[start + j + 4 + g];
        int s2 = csr[start + j + 8 + g];
        int s3 = csr[start + j + 12 + g];
        float2 r0 = yb[(size_t)s0 * 16 + l15];
        float2 r1 = yb[(size_t)s1 * 16 + l15];
        float2 r2 = yb[(size_t)s2 * 16 + l15];
        float2 r3 = yb[(size_t)s3 * 16 + l15];
        PKACC(p0, q0, r0); PKACC(p1, q1, r1);
        PKACC(p2, q2, r2); PKACC(p3, q3, r3);
    }
    for (; j + 8 <= c; j += 8) {            // 8 edges, 2 gathers in flight
        int s0 = csr[start + j + g];
        int s1 = csr[start + j + 4 + g];
        float2 r0 = yb[(size_t)s0 * 16 + l15];
        float2 r1 = yb[(size_t)s1 * 16 + l15];
        PKACC(p0, q0, r0); PKACC(p1, q1, r1);
    }
    for (; j < c; j += 4) {                 // predicated tail; clamp inside OWN row
        bool valid = (j + g) < c;
        int s = csr[start + min(j + g, c - 1)];
        float2 r = yb[(size_t)s * 16 + l15];
        if (valid) { PKACC(p0, q0, r); }
    }
    __half2 sp = __hadd2(__hadd2(p0, p1), __hadd2(p2, p3));
    __half2 sq = __hadd2(__hadd2(q0, q1), __hadd2(q2, q3));
    PKBFLY(sp, sq);
    float2 fp = __half22float2(sp), fq = __half22float2(sq);
    float4 tot = make_float4(fp.x, fp.y, fq.x, fq.y);
    float4 sv = h4_to_f4(yb[(size_t)node * 16 + l15]);
    float dn = dis[node];
    float4 b1f = ((const float4*)b1)[l15];
    float ox = dn * fmaxf(dn * (tot.x + sv.x) + b1f.x, 0.f);
    float oy = dn * fmaxf(dn * (tot.y + sv.y) + b1f.y, 0.f);
    float oz = dn * fmaxf(dn * (tot.z + sv.z) + b1f.z, 0.f);
    float ow = dn * fmaxf(dn * (tot.w + sv.w) + b1f.w, 0.f);
    if (g == 0) {
        __half2 ha; ha.x = __float2half(ox); ha.y = __float2half(oy);
        __half2 hb; hb.x = __float2half(oz); hb.y = __float2half(ow);
        float2 st;
        st.x = *reinterpret_cast<float*>(&ha);
        st.y = *reinterpret_cast<float*>(&hb);
        ((float2*)h1h)[(size_t)node * 16 + l15] = st;
    }
}

// ---------------- y23h = fp16( h1h @ (W2 ‖ W3) ), interleaved mu/lv rows ----------------
__global__ void k_mm2(const __half* __restrict__ h1h,
                      const float* __restrict__ W2, const float* __restrict__ W3,
                      __half* __restrict__ y23h) {
    __shared__ float sW2[H1 * H2];
    __shared__ float sW3[H1 * H2];
    __shared__ float sh[8 * H1];
    int t = threadIdx.x;
    for (int i = t; i < H1 * H2; i += 256) { sW2[i] = W2[i]; sW3[i] = W3[i]; }
    int base_n = blockIdx.x * 8;
    const __half2* hp = (const __half2*)h1h;
    for (int i = t; i < 8 * 32; i += 256) {      // 256 half2 loads
        int n = base_n + (i >> 5);
        float2 f = (n < NN) ? __half22float2(hp[(size_t)n * 32 + (i & 31)])
                            : make_float2(0.f, 0.f);
        ((float2*)sh)[i] = f;
    }
    __syncthreads();
    int n = base_n + (t >> 5), h = t & 31;
    if (n < NN) {
        float a2 = 0.f, a3 = 0.f;
        const float* hr = &sh[(t >> 5) * H1];
#pragma unroll
        for (int k = 0; k < H1; k++) {
            float hv = hr[k];
            a2 += hv * sW2[k * H2 + h];
            a3 += hv * sW3[k * H2 + h];
        }
        y23h[(size_t)n * 64 + h]      = __float2half(a2);
        y23h[(size_t)n * 64 + 32 + h] = __float2half(a3);
    }
}

// ---------------- layer-2 aggregation + fused epilogue ----------------
// y23h row: halves 0..31 = mu-path, 32..63 = logvar-path
__global__ __launch_bounds__(256) void k_agg2(const int2* __restrict__ rowinfo,
                                              const float* __restrict__ dis,
                                              const int* __restrict__ csr,
                                              const __half* __restrict__ y23h,
                                              const float* __restrict__ b2,
                                              const float* __restrict__ b3,
                                              const float* __restrict__ eps,
                                              float* __restrict__ out_z,
                                              float* __restrict__ out_mu,
                                              float* __restrict__ out_lv) {
    int node = (blockIdx.x * 256 + threadIdx.x) >> 6;
    int lane = threadIdx.x & 63;
    if (node >= NN) return;
    int g = lane >> 4, l15 = lane & 15;
    int2 ri = rowinfo[node];
    int start = ri.x, c = ri.y;
    const float2* yb = (const float2*)y23h;
    __half2 z = __float2half2_rn(0.f);
    __half2 p0 = z, p1 = z, p2 = z, p3 = z;
    __half2 q0 = z, q1 = z, q2 = z, q3 = z;
    int j = 0;
    for (; j + 16 <= c; j += 16) {
        int s0 = csr[start + j + g];
        int s1 = csr[start + j + 4 + g];
        int s2 = csr[start + j + 8 + g];
        int s3 = csr[start + j + 12 + g];
        float2 r0 = yb[(size_t)s0 * 16 + l15];
        float2 r1 = yb[(size_t)s1 * 16 + l15];
        float2 r2 = yb[(size_t)s2 * 16 + l15];
        float2 r3 = yb[(size_t)s3 * 16 + l15];
        PKACC(p0, q0, r0); PKACC(p1, q1, r1);
        PKACC(p2, q2, r2); PKACC(p3, q3, r3);
    }
    for (; j + 8 <= c; j += 8) {
        int s0 = csr[start + j + g];
        int s1 = csr[start + j + 4 + g];
        float2 r0 = yb[(size_t)s0 * 16 + l15];
        float2 r1 = yb[(size_t)s1 * 16 + l15];
        PKACC(p0, q0, r0); PKACC(p1, q1, r1);
    }
    for (; j < c; j += 4) {
        bool valid = (j + g) < c;
        int s = csr[start + min(j + g, c - 1)];
        float2 r = yb[(size_t)s * 16 + l15];
        if (valid) { PKACC(p0, q0, r); }
    }
    __half2 sp = __hadd2(__hadd2(p0, p1), __hadd2(p2, p3));
    __half2 sq = __hadd2(__hadd2(q0, q1), __hadd2(q2, q3));
    PKBFLY(sp, sq);
    float2 fp = __half22float2(sp), fq = __half22float2(sq);
    float4 tot = make_float4(fp.x, fp.y, fq.x, fq.y);
    float4 sv = h4_to_f4(yb[(size_t)node * 16 + l15]);
    float dn = dis[node];
    float4 bias = (l15 < 8) ? ((const float4*)b2)[l15] : ((const float4*)b3)[l15 - 8];
    float4 val;
    val.x = fmaxf(dn * (tot.x + sv.x) + bias.x, 0.f);
    val.y = fmaxf(dn * (tot.y + sv.y) + bias.y, 0.f);
    val.z = fmaxf(dn * (tot.z + sv.z) + bias.z, 0.f);
    val.w = fmaxf(dn * (tot.w + sv.w) + bias.w, 0.f);
    float4 other;
    other.x = __shfl_xor(val.x, 8, 64);
    other.y = __shfl_xor(val.y, 8, 64);
    other.z = __shfl_xor(val.z, 8, 64);
    other.w = __shfl_xor(val.w, 8, 64);
    if (g == 0) {
        if (l15 < 8) {
            size_t q = (size_t)node * 8 + l15;
            ((float4*)out_mu)[q] = val;
            float4 ev = ((const float4*)eps)[q];
            float4 zz;
            zz.x = ev.x * __expf(other.x) + val.x;
            zz.y = ev.y * __expf(other.y) + val.y;
            zz.z = ev.z * __expf(other.z) + val.z;
            zz.w = ev.w * __expf(other.w) + val.w;
            ((float4*)out_z)[q] = zz;
        } else {
            ((float4*)out_lv)[(size_t)node * 8 + (l15 - 8)] = val;
        }
    }
}

extern "C" void kernel_launch(void* const* d_in, const int* in_sizes, int n_in,
                              void* d_out, int out_size, void* d_ws, size_t ws_size,
                              hipStream_t stream) {
    const float* x   = (const float*)d_in[0];
    const int*   ei  = (const int*)d_in[1];   // [2, E]
    const int*   bat = (const int*)d_in[2];
    const float* W1  = (const float*)d_in[3];
    const float* b1  = (const float*)d_in[4];
    const float* W2  = (const float*)d_in[5];
    const float* b2  = (const float*)d_in[6];
    const float* W3  = (const float*)d_in[7];
    const float* b3  = (const float*)d_in[8];
    const float* eps = (const float*)d_in[9];

    const int* src = ei;
    const int* dst = ei + NE;

    float* out = (float*)d_out;
    float* out_z    = out;                               // [N,32]
    float* out_pool = out + (size_t)NN * H2;             // [G,7]
    float* out_mu   = out_pool + NG * D_IN;              // [N,32]
    float* out_lv   = out_mu + (size_t)NN * H2;          // [N,32]

    // workspace layout (8B-aligned segments)
    int*    bucket_cursor = (int*)d_ws;                          // 256
    int2*   rowinfo       = (int2*)(bucket_cursor + 256);        // NN (start,cnt)
    float*  dis           = (float*)(rowinfo + NN);              // NN
    int2*   staging       = (int2*)(dis + NN);                   // NBUK*CAP
    int*    csr           = (int*)(staging + (size_t)NBUK * CAP);// NBUK*CAP
    __half* y1h           = (__half*)(csr + (size_t)NBUK * CAP); // NN*64 halves
    __half* h1h           = y1h + (size_t)NN * H1;               // NN*64 halves
    __half* y23h          = y1h;                                 // alias: y1h dead after k_agg1

    k_init  <<<1, 256, 0, stream>>>(bucket_cursor);
    k_bin   <<<NTILE, 256, 0, stream>>>(src, dst, bucket_cursor, staging);
    k_build <<<NBUK, 512, 0, stream>>>(staging, bucket_cursor, rowinfo, dis, csr);

    k_pool  <<<NG, 256, 0, stream>>>(x, bat, out_pool);

    k_mm1   <<<(NN * H1 + 255) / 256, 256, 0, stream>>>(x, W1, dis, y1h);
    k_agg1  <<<(NN + 3) / 4, 256, 0, stream>>>(rowinfo, dis, csr, y1h, b1, h1h);
    k_mm2   <<<(NN + 7) / 8, 256, 0, stream>>>(h1h, W2, W3, y23h);
    k_agg2  <<<(NN + 3) / 4, 256, 0, stream>>>(rowinfo, dis, csr, y23h,
                                               b2, b3, eps, out_z, out_mu, out_lv);
}

// Round 11
// 263.542 us; speedup vs baseline: 1.3455x; 1.1235x over previous
//
#include <hip/hip_runtime.h>
#include <hip/hip_bf16.h>
#include <hip/hip_fp16.h>

#define NN 100000
#define NE 1600000
#define D_IN 7
#define H1 64
#define H2 32
#define NG 64
#define TE 2048          // edges per bin tile
#define NTILE 782        // ceil(NE/TE)
#define BSH 9            // bucket = dst >> 9  (512 nodes/bucket)
#define NBUK 196         // ceil(NN/512)
#define CAP 10240        // slots per bucket (mean 8192, +22 sigma)

// ---------------- init bucket cursors to b*CAP ----------------
__global__ void k_init(int* __restrict__ bucket_cursor) {
    int t = threadIdx.x;
    if (t < 256) bucket_cursor[t] = t * CAP;
}

// ---------------- bin edges into fixed-capacity buckets (coalesced flush) ----------------
__global__ __launch_bounds__(256) void k_bin(const int* __restrict__ src,
                                             const int* __restrict__ dst,
                                             int* __restrict__ bucket_cursor,
                                             int* __restrict__ staging) {
    __shared__ int hist[NBUK];
    __shared__ int startx[NBUK];
    __shared__ int runb[NBUK];
    __shared__ int cur[NBUK];
    __shared__ int sc[256];
    __shared__ int2 pairs[TE];
    int t = threadIdx.x;
    int base = blockIdx.x * TE;
    int tile_cnt = min(TE, NE - base);
    for (int i = t; i < NBUK; i += 256) hist[i] = 0;
    __syncthreads();
    int myd[TE / 256], mys[TE / 256];
#pragma unroll
    for (int k = 0; k < TE / 256; k++) {
        int i = base + k * 256 + t;
        if (i < NE) {
            myd[k] = dst[i]; mys[k] = src[i];
            atomicAdd(&hist[myd[k] >> BSH], 1);
        } else myd[k] = -1;
    }
    __syncthreads();
    int hv = (t < NBUK) ? hist[t] : 0;
    sc[t] = hv;
    __syncthreads();
    for (int off = 1; off < 256; off <<= 1) {
        int add = (t >= off) ? sc[t - off] : 0;
        __syncthreads();
        sc[t] += add;
        __syncthreads();
    }
    if (t < NBUK) {
        int ex = sc[t] - hv;
        startx[t] = ex;
        cur[t] = ex;
        if (hv > 0) runb[t] = atomicAdd(&bucket_cursor[t], hv);
    }
    __syncthreads();
#pragma unroll
    for (int k = 0; k < TE / 256; k++) {
        if (myd[k] >= 0) {
            int b = myd[k] >> BSH;
            int slot = atomicAdd(&cur[b], 1);
            pairs[slot] = make_int2(myd[k], mys[k]);
        }
    }
    __syncthreads();
    for (int i = t; i < tile_cnt; i += 256) {   // pack (local<<17)|src at flush
        int2 p = pairs[i];
        int b = p.x >> BSH;
        staging[runb[b] + (i - startx[b])] = ((p.x & 511) << 17) | p.y;
    }
}

// ---------------- per-bucket CSR finalize: rowinfo, dis, dense scatter ----------------
__global__ __launch_bounds__(512) void k_build(const int* __restrict__ staging,
                                               const int* __restrict__ bucket_cursor,
                                               int2* __restrict__ rowinfo,
                                               float* __restrict__ dis,
                                               int* __restrict__ csr) {
    __shared__ int cnt[512];
    __shared__ int offs[512];
    __shared__ int cur[512];
    int t = threadIdx.x;
    int nbase = blockIdx.x << BSH;
    int ebase = blockIdx.x * CAP;
    int eend = bucket_cursor[blockIdx.x];   // ebase + count
    cnt[t] = 0;
    __syncthreads();
    for (int i = ebase + t; i < eend; i += 512)
        atomicAdd(&cnt[staging[i] >> 17], 1);
    __syncthreads();
    int v = cnt[t];
    offs[t] = v;
    __syncthreads();
    for (int off = 1; off < 512; off <<= 1) {
        int add = (t >= off) ? offs[t - off] : 0;
        __syncthreads();
        offs[t] += add;
        __syncthreads();
    }
    int excl = offs[t] - v;
    cur[t] = excl;
    int node = nbase + t;
    if (node < NN) {
        rowinfo[node] = make_int2(ebase + excl, v);
        dis[node] = rsqrtf((float)v + 1.0f);
    }
    __syncthreads();
    for (int i = ebase + t; i < eend; i += 512) {
        int p = staging[i];
        int pos = ebase + atomicAdd(&cur[p >> 17], 1);
        csr[pos] = p & 0x1FFFF;   // stores confined to bucket's ~40KB csr window
    }
}

// ---------------- mean pool over sorted batch ----------------
__device__ int lower_bound_i(const int* a, int n, int v) {
    int lo = 0, hi = n;
    while (lo < hi) { int mid = (lo + hi) >> 1; if (a[mid] < v) lo = mid + 1; else hi = mid; }
    return lo;
}

__global__ void k_pool(const float* __restrict__ x, const int* __restrict__ batch,
                       float* __restrict__ outp) {
    __shared__ int bounds[2];
    __shared__ float red[256 * D_IN];
    int g = blockIdx.x, t = threadIdx.x;
    if (t == 0) {
        bounds[0] = lower_bound_i(batch, NN, g);
        bounds[1] = lower_bound_i(batch, NN, g + 1);
    }
    __syncthreads();
    int s = bounds[0], e = bounds[1];
    float acc[D_IN];
#pragma unroll
    for (int k = 0; k < D_IN; k++) acc[k] = 0.f;
    for (int n = s + t; n < e; n += 256) {
#pragma unroll
        for (int k = 0; k < D_IN; k++) acc[k] += x[n * D_IN + k];
    }
#pragma unroll
    for (int k = 0; k < D_IN; k++) red[t * D_IN + k] = acc[k];
    __syncthreads();
    if (t < D_IN) {
        float sum = 0.f;
        for (int i = 0; i < 256; i++) sum += red[i * D_IN + t];
        float cnt = (float)(e - s);
        outp[g * D_IN + t] = sum / fmaxf(cnt, 1.f);
    }
}

// ---------------- y1h = fp16( dis * (x @ W1) ) ----------------
__global__ void k_mm1(const float* __restrict__ x, const float* __restrict__ W1,
                      const float* __restrict__ dis, __half* __restrict__ y1h) {
    __shared__ float sW[D_IN * H1];
    int t = threadIdx.x;
    for (int i = t; i < D_IN * H1; i += 256) sW[i] = W1[i];
    __syncthreads();
    int idx = blockIdx.x * 256 + t;
    if (idx < NN * H1) {
        int n = idx >> 6, h = idx & 63;
        float a = 0.f;
#pragma unroll
        for (int k = 0; k < D_IN; k++) a += x[n * D_IN + k] * sW[k * H1 + h];
        y1h[idx] = __float2half(a * dis[n]);
    }
}

// convert 4 packed halves (as float2 raw) to float4
__device__ __forceinline__ float4 h4_to_f4(float2 r) {
    __half2 h0 = *reinterpret_cast<__half2*>(&r.x);
    __half2 h1 = *reinterpret_cast<__half2*>(&r.y);
    float2 f0 = __half22float2(h0);
    float2 f1 = __half22float2(h1);
    return make_float4(f0.x, f0.y, f1.x, f1.y);
}

// masked packed accumulate: p,q += r (as 4 halves) if v
__device__ __forceinline__ void pk_acc_m(__half2& p, __half2& q, float2 r, bool v) {
    unsigned ux = v ? *reinterpret_cast<unsigned*>(&r.x) : 0u;
    unsigned uy = v ? *reinterpret_cast<unsigned*>(&r.y) : 0u;
    p = __hadd2(p, *reinterpret_cast<__half2*>(&ux));
    q = __hadd2(q, *reinterpret_cast<__half2*>(&uy));
}

// ---------------- layer-1 agg + fused bias/relu: h1h = fp16( dis * relu(agg + b1) ) ----------------
// wave handles 4 consecutive nodes; sub = lane>>4, l15 = lane&15 (channel quad).
// No cross-lane reduction: each node's 16 lanes hold the full 64-ch row.
__global__ __launch_bounds__(256) void k_agg1(const int2* __restrict__ rowinfo,
                                              const float* __restrict__ dis,
                                              const int* __restrict__ csr,
                                              const __half* __restrict__ y1h,
                                              const float* __restrict__ b1,
                                              __half* __restrict__ h1h) {
    int t = threadIdx.x;
    int wave = (blockIdx.x * 256 + t) >> 6;
    int lane = t & 63;
    int sub = lane >> 4, l15 = lane & 15;
    int node = wave * 4 + sub;                 // NN = 6250*16 exactly
    int2 ri = rowinfo[node];
    int start = ri.x, c = ri.y;
    int cpos = start + max(c - 1, 0);
    int cmax = c;
    cmax = max(cmax, __shfl_xor(cmax, 16, 64));
    cmax = max(cmax, __shfl_xor(cmax, 32, 64));
    const float2* yb = (const float2*)y1h;
    __half2 z2 = __float2half2_rn(0.f);
    __half2 p[4] = {z2, z2, z2, z2};
    __half2 q[4] = {z2, z2, z2, z2};
    for (int j = 0; j < cmax; j += 8) {        // 8 gathers in flight = 32 edges/wave
#pragma unroll
        for (int k = 0; k < 8; k++) {
            bool v = (j + k) < c;
            int s = csr[min(start + j + k, cpos)];
            s = v ? s : node;
            float2 r = yb[(size_t)s * 16 + l15];
            pk_acc_m(p[k & 3], q[k & 3], r, v);
        }
    }
    __half2 sp = __hadd2(__hadd2(p[0], p[1]), __hadd2(p[2], p[3]));
    __half2 sq = __hadd2(__hadd2(q[0], q[1]), __hadd2(q[2], q[3]));
    float2 fp = __half22float2(sp), fq = __half22float2(sq);
    float4 sv = h4_to_f4(yb[(size_t)node * 16 + l15]);   // self term
    float dn = dis[node];
    float4 b1f = ((const float4*)b1)[l15];
    float ox = dn * fmaxf(dn * (fp.x + sv.x) + b1f.x, 0.f);
    float oy = dn * fmaxf(dn * (fp.y + sv.y) + b1f.y, 0.f);
    float oz = dn * fmaxf(dn * (fq.x + sv.z) + b1f.z, 0.f);
    float ow = dn * fmaxf(dn * (fq.y + sv.w) + b1f.w, 0.f);
    __half2 ha; ha.x = __float2half(ox); ha.y = __float2half(oy);
    __half2 hb; hb.x = __float2half(oz); hb.y = __float2half(ow);
    float2 st;
    st.x = *reinterpret_cast<float*>(&ha);
    st.y = *reinterpret_cast<float*>(&hb);
    ((float2*)h1h)[(size_t)node * 16 + l15] = st;        // all 64 lanes store: 512B/wave
}

// ---------------- y23h = fp16( h1h @ (W2 ‖ W3) ), interleaved mu/lv rows ----------------
__global__ void k_mm2(const __half* __restrict__ h1h,
                      const float* __restrict__ W2, const float* __restrict__ W3,
                      __half* __restrict__ y23h) {
    __shared__ float sW2[H1 * H2];
    __shared__ float sW3[H1 * H2];
    __shared__ float sh[8 * H1];
    int t = threadIdx.x;
    for (int i = t; i < H1 * H2; i += 256) { sW2[i] = W2[i]; sW3[i] = W3[i]; }
    int base_n = blockIdx.x * 8;
    const __half2* hp = (const __half2*)h1h;
    for (int i = t; i < 8 * 32; i += 256) {
        int n = base_n + (i >> 5);
        float2 f = (n < NN) ? __half22float2(hp[(size_t)n * 32 + (i & 31)])
                            : make_float2(0.f, 0.f);
        ((float2*)sh)[i] = f;
    }
    __syncthreads();
    int n = base_n + (t >> 5), h = t & 31;
    if (n < NN) {
        float a2 = 0.f, a3 = 0.f;
        const float* hr = &sh[(t >> 5) * H1];
#pragma unroll
        for (int k = 0; k < H1; k++) {
            float hv = hr[k];
            a2 += hv * sW2[k * H2 + h];
            a3 += hv * sW3[k * H2 + h];
        }
        y23h[(size_t)n * 64 + h]      = __float2half(a2);
        y23h[(size_t)n * 64 + 32 + h] = __float2half(a3);
    }
}

// ---------------- layer-2 aggregation + fused epilogue (4 nodes/wave) ----------------
// y23h row: halves 0..31 = mu-path, 32..63 = logvar-path
__global__ __launch_bounds__(256) void k_agg2(const int2* __restrict__ rowinfo,
                                              const float* __restrict__ dis,
                                              const int* __restrict__ csr,
                                              const __half* __restrict__ y23h,
                                              const float* __restrict__ b2,
                                              const float* __restrict__ b3,
                                              const float* __restrict__ eps,
                                              float* __restrict__ out_z,
                                              float* __restrict__ out_mu,
                                              float* __restrict__ out_lv) {
    int t = threadIdx.x;
    int wave = (blockIdx.x * 256 + t) >> 6;
    int lane = t & 63;
    int sub = lane >> 4, l15 = lane & 15;
    int node = wave * 4 + sub;
    int2 ri = rowinfo[node];
    int start = ri.x, c = ri.y;
    int cpos = start + max(c - 1, 0);
    int cmax = c;
    cmax = max(cmax, __shfl_xor(cmax, 16, 64));
    cmax = max(cmax, __shfl_xor(cmax, 32, 64));
    const float2* yb = (const float2*)y23h;
    __half2 z2 = __float2half2_rn(0.f);
    __half2 p[4] = {z2, z2, z2, z2};
    __half2 q[4] = {z2, z2, z2, z2};
    for (int j = 0; j < cmax; j += 8) {
#pragma unroll
        for (int k = 0; k < 8; k++) {
            bool v = (j + k) < c;
            int s = csr[min(start + j + k, cpos)];
            s = v ? s : node;
            float2 r = yb[(size_t)s * 16 + l15];
            pk_acc_m(p[k & 3], q[k & 3], r, v);
        }
    }
    __half2 sp = __hadd2(__hadd2(p[0], p[1]), __hadd2(p[2], p[3]));
    __half2 sq = __hadd2(__hadd2(q[0], q[1]), __hadd2(q[2], q[3]));
    float2 fp = __half22float2(sp), fq = __half22float2(sq);
    float4 sv = h4_to_f4(yb[(size_t)node * 16 + l15]);
    float dn = dis[node];
    float4 bias = (l15 < 8) ? ((const float4*)b2)[l15] : ((const float4*)b3)[l15 - 8];
    float4 val;
    val.x = fmaxf(dn * (fp.x + sv.x) + bias.x, 0.f);
    val.y = fmaxf(dn * (fp.y + sv.y) + bias.y, 0.f);
    val.z = fmaxf(dn * (fq.x + sv.z) + bias.z, 0.f);
    val.w = fmaxf(dn * (fq.y + sv.w) + bias.w, 0.f);
    float4 other;                              // xor 8 pairs mu-quad with lv-quad (same sub)
    other.x = __shfl_xor(val.x, 8, 64);
    other.y = __shfl_xor(val.y, 8, 64);
    other.z = __shfl_xor(val.z, 8, 64);
    other.w = __shfl_xor(val.w, 8, 64);
    if (l15 < 8) {
        size_t qi = (size_t)node * 8 + l15;
        ((float4*)out_mu)[qi] = val;
        float4 ev = ((const float4*)eps)[qi];
        float4 zz;
        zz.x = ev.x * __expf(other.x) + val.x;
        zz.y = ev.y * __expf(other.y) + val.y;
        zz.z = ev.z * __expf(other.z) + val.z;
        zz.w = ev.w * __expf(other.w) + val.w;
        ((float4*)out_z)[qi] = zz;
    } else {
        ((float4*)out_lv)[(size_t)node * 8 + (l15 - 8)] = val;
    }
}

extern "C" void kernel_launch(void* const* d_in, const int* in_sizes, int n_in,
                              void* d_out, int out_size, void* d_ws, size_t ws_size,
                              hipStream_t stream) {
    const float* x   = (const float*)d_in[0];
    const int*   ei  = (const int*)d_in[1];   // [2, E]
    const int*   bat = (const int*)d_in[2];
    const float* W1  = (const float*)d_in[3];
    const float* b1  = (const float*)d_in[4];
    const float* W2  = (const float*)d_in[5];
    const float* b2  = (const float*)d_in[6];
    const float* W3  = (const float*)d_in[7];
    const float* b3  = (const float*)d_in[8];
    const float* eps = (const float*)d_in[9];

    const int* src = ei;
    const int* dst = ei + NE;

    float* out = (float*)d_out;
    float* out_z    = out;                               // [N,32]
    float* out_pool = out + (size_t)NN * H2;             // [G,7]
    float* out_mu   = out_pool + NG * D_IN;              // [N,32]
    float* out_lv   = out_mu + (size_t)NN * H2;          // [N,32]

    // workspace layout (8B-aligned segments)
    int*    bucket_cursor = (int*)d_ws;                          // 256
    int2*   rowinfo       = (int2*)(bucket_cursor + 256);        // NN (start,cnt)
    float*  dis           = (float*)(rowinfo + NN);              // NN
    int*    staging       = (int*)(dis + NN);                    // NBUK*CAP packed ints
    int*    csr           = staging + (size_t)NBUK * CAP;        // NBUK*CAP
    __half* y1h           = (__half*)(csr + (size_t)NBUK * CAP); // NN*64 halves
    __half* h1h           = y1h + (size_t)NN * H1;               // NN*64 halves
    __half* y23h          = y1h;                                 // alias: y1h dead after k_agg1

    k_init  <<<1, 256, 0, stream>>>(bucket_cursor);
    k_bin   <<<NTILE, 256, 0, stream>>>(src, dst, bucket_cursor, staging);
    k_build <<<NBUK, 512, 0, stream>>>(staging, bucket_cursor, rowinfo, dis, csr);

    k_pool  <<<NG, 256, 0, stream>>>(x, bat, out_pool);

    k_mm1   <<<(NN * H1 + 255) / 256, 256, 0, stream>>>(x, W1, dis, y1h);
    k_agg1  <<<NN / 16, 256, 0, stream>>>(rowinfo, dis, csr, y1h, b1, h1h);
    k_mm2   <<<(NN + 7) / 8, 256, 0, stream>>>(h1h, W2, W3, y23h);
    k_agg2  <<<NN / 16, 256, 0, stream>>>(rowinfo, dis, csr, y23h,
                                          b2, b3, eps, out_z, out_mu, out_lv);
}